// Round 10
// baseline (209.506 us; speedup 1.0000x reference)
//
#include <hip/hip_runtime.h>
#include <math.h>

#define NQ    6
#define QDIM  64
#define BB    128
#define CC    64
#define TT    2048
#define DD    256
#define NCH   128
#define CHLEN 16
#define HH    128
#define NCP   60

typedef __bf16 bf16x8 __attribute__((ext_vector_type(8)));
typedef float  f32x4  __attribute__((ext_vector_type(4)));

__device__ __forceinline__ unsigned short bfbits(__bf16 v) {
  return __builtin_bit_cast(unsigned short, v);
}

__device__ __forceinline__ float fast_tanh(float x) {
  float e = __expf(2.f * x);
  return 1.f - 2.f / (e + 1.f);
}

__device__ __forceinline__ float wave_sum(float v) {
#pragma unroll
  for (int off = 32; off >= 1; off >>= 1) v += __shfl_xor(v, off, 64);
  return v;
}

// ---- quantum gates (k3 path keeps the trig-per-gate form; k1 uses fused) ----
__device__ __forceinline__ void g_rx(float& re, float& im, int lane, int m, float half) {
  float c = __cosf(half), s = __sinf(half);
  float pre = __shfl_xor(re, m, 64);
  float pim = __shfl_xor(im, m, 64);
  float nre = c * re + s * pim;
  float nim = c * im - s * pre;
  re = nre; im = nim;
}
__device__ __forceinline__ void g_ry(float& re, float& im, int lane, int m, float half) {
  float c = __cosf(half), s = __sinf(half);
  float pre = __shfl_xor(re, m, 64);
  float pim = __shfl_xor(im, m, 64);
  float sg = (lane & m) ? s : -s;
  re = c * re + sg * pre;
  im = c * im + sg * pim;
}
__device__ __forceinline__ void g_rz(float& re, float& im, int lane, int m, float half) {
  float c = __cosf(half), s = __sinf(half);
  float sg = (lane & m) ? s : -s;
  float nre = c * re - sg * im;
  float nim = c * im + sg * re;
  re = nre; im = nim;
}
__device__ __forceinline__ void g_crx(float& re, float& im, int lane, int mc, int mt, float half) {
  float c = __cosf(half), s = __sinf(half);
  float pre = __shfl_xor(re, mt, 64);
  float pim = __shfl_xor(im, mt, 64);
  if (lane & mc) {
    float nre = c * re + s * pim;
    float nim = c * im - s * pre;
    re = nre; im = nim;
  }
}
__device__ __forceinline__ void ansatz_layer(float& re, float& im, int lane,
                                             const float* p) {
#pragma unroll
  for (int q = 0; q < 6; ++q) {
    int m = 1 << (5 - q);
    g_rx(re, im, lane, m, 0.5f * p[3 * q + 0]);
    g_ry(re, im, lane, m, 0.5f * p[3 * q + 1]);
    g_rz(re, im, lane, m, 0.5f * p[3 * q + 2]);
  }
#pragma unroll
  for (int q = 0; q < 6; ++q)
    g_crx(re, im, lane, 1 << (5 - q), 1 << (5 - ((q + 1) % 6)), 0.5f * p[18 + q]);
#pragma unroll
  for (int q = 5; q >= 0; --q)
    g_crx(re, im, lane, 1 << (5 - q), 1 << (5 - ((q + 5) % 6)), 0.5f * p[24 + (5 - q)]);
}

// ============ K0: fused-weight prep, 8-way split-K (390 blocks) =============
__global__ __launch_bounds__(256) void k0_prep(
    const float* __restrict__ emb_w, const float* __restrict__ emb_b,
    const float* __restrict__ att_w1, const float* __restrict__ att_b1,
    const float* __restrict__ proj_w, const float* __restrict__ proj_b,
    __bf16* __restrict__ WfH, __bf16* __restrict__ WfL,
    __bf16* __restrict__ PfH, __bf16* __restrict__ PfL,
    float* __restrict__ b_fused, float* __restrict__ pb_fused) {
  int idx = blockIdx.x * 256 + threadIdx.x;
  if (idx < 65536) {                        // W_fusedT: 8192 outs x 8 parts
    int out = idx >> 3, part = idx & 7;
    int j = out & 127, k = out >> 7;
    int d0 = part * 32;
    float a = 0.f;
#pragma unroll 8
    for (int d = d0; d < d0 + 32; ++d)
      a = fmaf(emb_w[k * 256 + d], att_w1[d * 128 + j], a);
    a += __shfl_xor(a, 1, 64); a += __shfl_xor(a, 2, 64); a += __shfl_xor(a, 4, 64);
    if (part == 0) {
      __bf16 h = (__bf16)a;
      WfH[j * 64 + k] = h; WfL[j * 64 + k] = (__bf16)(a - (float)h);
    }
  } else if (idx < 98304) {                 // P_fusedT: 4096 outs x 8 parts
    int i2 = idx - 65536;
    int out = i2 >> 3, part = i2 & 7;
    int n = out & 63, k = out >> 6;
    float a = 0.f;
    if (n < 60) {
      int d0 = part * 32;
#pragma unroll 8
      for (int d = d0; d < d0 + 32; ++d)
        a = fmaf(emb_w[k * 256 + d], proj_w[d * 60 + n], a);
    }
    a += __shfl_xor(a, 1, 64); a += __shfl_xor(a, 2, 64); a += __shfl_xor(a, 4, 64);
    if (part == 0) {
      __bf16 h = (__bf16)a;
      PfH[n * 64 + k] = h; PfL[n * 64 + k] = (__bf16)(a - (float)h);
    }
  } else if (idx < 99328) {                 // b_fused: 128 outs x 8
    int i3 = idx - 98304;
    int out = i3 >> 3, part = i3 & 7;
    float a = (part == 0) ? att_b1[out] : 0.f;
    int d0 = part * 32;
#pragma unroll 8
    for (int d = d0; d < d0 + 32; ++d)
      a = fmaf(emb_b[d], att_w1[d * 128 + out], a);
    a += __shfl_xor(a, 1, 64); a += __shfl_xor(a, 2, 64); a += __shfl_xor(a, 4, 64);
    if (part == 0) b_fused[out] = a;
  } else if (idx < 99840) {                 // pb_fused: 64 outs x 8
    int i4 = idx - 99328;
    int out = i4 >> 3, part = i4 & 7;
    float a = 0.f;
    if (out < 60) {
      if (part == 0) a = proj_b[out];
      int d0 = part * 32;
#pragma unroll 8
      for (int d = d0; d < d0 + 32; ++d)
        a = fmaf(emb_b[d], proj_w[d * 60 + out], a);
    }
    a += __shfl_xor(a, 1, 64); a += __shfl_xor(a, 2, 64); a += __shfl_xor(a, 4, 64);
    if (part == 0) pb_fused[out] = a;
  }
}

// ============ K1: fused h-GEMM + softmax + bilinear params + ansatz ==========
// R9 structure + unified-register squeeze to <=64 (VGPR+AGPR share one file;
// 68 total put us in the 4-waves/SIMD quantum -- m69: 8 waves at <=64):
//  - phase C: jt-split, acc[2] (8 AGPR) + partial-score fold per jt
//  - phase F': two 2-chunk passes, accp[2] (8 AGPR), P-frags reloaded (L2-hot)
//  - __launch_bounds__(256, 8): pin 8 blocks/CU (8 x 19968B LDS = 159.7KB fits)
// Spill tripwire: WRITE_SIZE must stay ~8.2MB (R3's force ballooned it to 73MB).
__global__ __launch_bounds__(256, 8) void k1_fused(
    const float* __restrict__ x, const float* __restrict__ att_w2,
    const __bf16* __restrict__ WfH, const __bf16* __restrict__ WfL,
    const __bf16* __restrict__ PfH, const __bf16* __restrict__ PfL,
    const float* __restrict__ b_fused, const float* __restrict__ pb_fused,
    float2* __restrict__ evolved) {
  const int blk = blockIdx.x;            // 4096 = 128 b x 32 chunk-quads
  const int b = blk >> 5, cq = blk & 31;
  const int tid = threadIdx.x, wv = tid >> 6, lane = tid & 63;
  const int l15 = lane & 15, quad = lane >> 4;

  __shared__ float4 afF4[1024];          // 16 KB split-bf16 A-frags (H | L)
  __shared__ float4 uniB[144];           // 2304 B: scoreS (C-D) | matS+crxS (F'-H)
  __shared__ __align__(16) float wSm[4][16];   // 256 B (live in F')
  __shared__ float paramsS[4][60];       // 960 B (written F', read G)
  float*  scoreS = (float*)uniB;         // [4][64] floats, phases C-D only
  float4* matS   = uniB;                 // [96], phases G-H (after scoreS dead)
  float2* crxS   = (float2*)(uniB + 96); // [96], phases F'-H (no scoreS overlap)

  bf16x8* afH = (bf16x8*)afF4;                       // [8 frag][64 lane]
  bf16x8* afL = (bf16x8*)((char*)afF4 + 8192);

  {  // A: stage x -> split-bf16 MFMA fragments directly (k-pairs, ushort2)
    unsigned short* afHu = (unsigned short*)afF4;
    unsigned short* afLu = (unsigned short*)((char*)afF4 + 8192);
#pragma unroll
    for (int p = 0; p < 2; ++p) {
      int slot = p * 256 + tid;
      int t4 = slot & 15, kp = slot >> 4;       // kp 0..31
      int k0 = kp * 2;
      const float* base = x + ((size_t)(b * 64 + k0)) * 2048 + cq * 64 + t4 * 4;
      float4 v0 = *(const float4*)base;
      float4 v1 = *(const float4*)(base + 2048);
      int ks = k0 >> 5, colq = (k0 >> 3) & 3, e = k0 & 7;
      float a0[4] = {v0.x, v0.y, v0.z, v0.w};
      float a1[4] = {v1.x, v1.y, v1.z, v1.w};
#pragma unroll
      for (int dt = 0; dt < 4; ++dt) {
        int t = t4 * 4 + dt;
        int frag = (t >> 4) * 2 + ks;
        int ln = (t & 15) + colq * 16;
        int widx = frag * 512 + ln * 8 + e;     // ushort index (e even)
        __bf16 h0 = (__bf16)a0[dt]; __bf16 l0 = (__bf16)(a0[dt] - (float)h0);
        __bf16 h1 = (__bf16)a1[dt]; __bf16 l1 = (__bf16)(a1[dt] - (float)h1);
        *(ushort2*)(afHu + widx) = make_ushort2(bfbits(h0), bfbits(h1));
        *(ushort2*)(afLu + widx) = make_ushort2(bfbits(l0), bfbits(l1));
      }
    }
  }
  __syncthreads();

  // ---- C: GEMM_h, jt-split so only acc[2] (8 AGPR) live at a time ----
  {
    float w2v[2], b1v[2];
#pragma unroll
    for (int jt = 0; jt < 2; ++jt) {
      int j = wv * 32 + jt * 16 + l15;
      w2v[jt] = att_w2[j];
      b1v[jt] = b_fused[j];
    }
#pragma unroll
    for (int half = 0; half < 2; ++half) {
      float scp[2][4];                   // partial scores [mtl][r]
#pragma unroll
      for (int jt = 0; jt < 2; ++jt) {
        f32x4 acc[2];                    // [mtl] -- 8 AGPR only
        acc[0] = (f32x4){0.f, 0.f, 0.f, 0.f};
        acc[1] = (f32x4){0.f, 0.f, 0.f, 0.f};
#pragma unroll
        for (int ks = 0; ks < 2; ++ks) {
          const size_t row = (size_t)(wv * 32 + jt * 16 + l15) * 64 + ks * 32 + 8 * quad;
          bf16x8 bh = *(const bf16x8*)(WfH + row);
          bf16x8 bl = *(const bf16x8*)(WfL + row);
#pragma unroll
          for (int mtl = 0; mtl < 2; ++mtl) {
            int frag = (half * 2 + mtl) * 2 + ks;
            bf16x8 ah = afH[frag * 64 + lane];
            bf16x8 al = afL[frag * 64 + lane];
            acc[mtl] = __builtin_amdgcn_mfma_f32_16x16x32_bf16(ah, bh, acc[mtl], 0, 0, 0);
            acc[mtl] = __builtin_amdgcn_mfma_f32_16x16x32_bf16(al, bh, acc[mtl], 0, 0, 0);
            acc[mtl] = __builtin_amdgcn_mfma_f32_16x16x32_bf16(ah, bl, acc[mtl], 0, 0, 0);
          }
        }
        // fold this jt's tanh contribution into partial scores
#pragma unroll
        for (int mtl = 0; mtl < 2; ++mtl)
#pragma unroll
          for (int r = 0; r < 4; ++r) {
            float t = fast_tanh(acc[mtl][r] + b1v[jt]) * w2v[jt];
            if (jt == 0) scp[mtl][r] = t; else scp[mtl][r] += t;
          }
      }
      // reduce over the 16 j's in l15
#pragma unroll
      for (int mtl = 0; mtl < 2; ++mtl)
#pragma unroll
        for (int r = 0; r < 4; ++r) {
          float sc = scp[mtl][r];
          sc += __shfl_xor(sc, 1, 64);
          sc += __shfl_xor(sc, 2, 64);
          sc += __shfl_xor(sc, 4, 64);
          sc += __shfl_xor(sc, 8, 64);
          if (l15 == 0) scoreS[wv * 64 + (half * 2 + mtl) * 16 + quad * 4 + r] = sc;
        }
    }
  }
  __syncthreads();

  if (tid < 64) {  // D: parallel softmax, 16 lanes per chunk (att_b2 dropped)
    const int c = tid >> 4, t = tid & 15, ct = c * 16 + t;
    float s = (scoreS[0 * 64 + ct] + scoreS[1 * 64 + ct]) +
              (scoreS[2 * 64 + ct] + scoreS[3 * 64 + ct]);
    float mx = s;
    mx = fmaxf(mx, __shfl_xor(mx, 1, 64));
    mx = fmaxf(mx, __shfl_xor(mx, 2, 64));
    mx = fmaxf(mx, __shfl_xor(mx, 4, 64));
    mx = fmaxf(mx, __shfl_xor(mx, 8, 64));
    float e = __expf(s - mx);
    float sum = e;
    sum += __shfl_xor(sum, 1, 64);
    sum += __shfl_xor(sum, 2, 64);
    sum += __shfl_xor(sum, 4, 64);
    sum += __shfl_xor(sum, 8, 64);
    wSm[c][t] = e / sum;
  }
  __syncthreads();

  {  // F': XP GEMM in two 2-chunk passes (accp[2] = 8 AGPR) + bilinear reduce
    const size_t prow = (size_t)(wv * 16 + l15) * 64 + 8 * quad;
    float v[4];
#pragma unroll
    for (int g2 = 0; g2 < 2; ++g2) {
      f32x4 accp[2];
      accp[0] = (f32x4){0.f, 0.f, 0.f, 0.f};
      accp[1] = (f32x4){0.f, 0.f, 0.f, 0.f};
#pragma unroll
      for (int ks = 0; ks < 2; ++ks) {
        bf16x8 pbh = *(const bf16x8*)(PfH + prow + ks * 32);
        bf16x8 pbl = *(const bf16x8*)(PfL + prow + ks * 32);
#pragma unroll
        for (int mi = 0; mi < 2; ++mi) {
          int mt = g2 * 2 + mi;
          bf16x8 ah = afH[(mt * 2 + ks) * 64 + lane];
          bf16x8 al = afL[(mt * 2 + ks) * 64 + lane];
          accp[mi] = __builtin_amdgcn_mfma_f32_16x16x32_bf16(ah, pbh, accp[mi], 0, 0, 0);
          accp[mi] = __builtin_amdgcn_mfma_f32_16x16x32_bf16(al, pbh, accp[mi], 0, 0, 0);
          accp[mi] = __builtin_amdgcn_mfma_f32_16x16x32_bf16(ah, pbl, accp[mi], 0, 0, 0);
        }
      }
#pragma unroll
      for (int mi = 0; mi < 2; ++mi) {  // params_pre[c][n] = sum_t w[c][t]*XP
        int c = g2 * 2 + mi;
        float4 wq = *(const float4*)&wSm[c][quad * 4];
        float a = wq.x * accp[mi][0] + wq.y * accp[mi][1] +
                  wq.z * accp[mi][2] + wq.w * accp[mi][3];
        a += __shfl_xor(a, 16, 64);
        a += __shfl_xor(a, 32, 64);
        v[c] = a;
      }
    }
    const int n = wv * 16 + l15;
    if (quad == 0 && n < 60) {
      float pbias = pb_fused[n];
      const int layer = (n >= 30) ? 1 : 0;
      const int pm = n - layer * 30;
#pragma unroll
      for (int c = 0; c < 4; ++c) {
        float a = v[c] + pbias;
        float p = 1.f / (1.f + __expf(-a));
        paramsS[c][n] = p;
        if (pm >= 18) {                 // CRX param: stash (cos,sin) of half
          float sn, cs;
          __sincosf(0.5f * p, &sn, &cs);
          crxS[c * 24 + layer * 12 + (pm - 18)] = make_float2(cs, sn);
        }
      }
    }
  }
  __syncthreads();

  if (tid < 48) {  // G: fused 1q unitary U = Rz*Ry*Rx per (chunk,layer,qubit)
    const int r = tid / 12, g = tid % 12;      // g = layer*6 + q
    const float* pp = &paramsS[r][(g / 6) * 30 + (g % 6) * 3];
    float sa, ca, sb, cb, sg, cg;
    __sincosf(0.5f * pp[0], &sa, &ca);
    __sincosf(0.5f * pp[1], &sb, &cb);
    __sincosf(0.5f * pp[2], &sg, &cg);
    // M = Ry*Rx
    float m00r = cb * ca, m00i = sb * sa;
    float m01r = -sb * ca, m01i = -cb * sa;
    float m10r = sb * ca, m10i = -cb * sa;
    float m11r = cb * ca, m11i = -sb * sa;
    // row0 *= e^{-i g}; row1 *= e^{+i g}; store per-bit {diag, offdiag}
    float4 b0, b1;
    b0.x = cg * m00r + sg * m00i;  b0.y = cg * m00i - sg * m00r;   // U00
    b0.z = cg * m01r + sg * m01i;  b0.w = cg * m01i - sg * m01r;   // U01
    b1.x = cg * m11r - sg * m11i;  b1.y = cg * m11i + sg * m11r;   // U11
    b1.z = cg * m10r - sg * m10i;  b1.w = cg * m10i + sg * m10r;   // U10
    matS[(r * 12 + g) * 2 + 0] = b0;
    matS[(r * 12 + g) * 2 + 1] = b1;
  }
  __syncthreads();

  // ---- H: ALL 4 waves evolve one chunk each (trig-free loop) ----
  {
    float re = (lane == 0) ? 1.f : 0.f, im = 0.f;
    const float4* mats = &matS[wv * 24];   // [12][2]
    const float2* crxs = &crxS[wv * 24];   // [2][12]
#pragma unroll
    for (int l = 0; l < 2; ++l) {
      float4 cpk[6];                       // this layer's 12 (cos,sin) pairs
      const float4* cv = (const float4*)&crxs[l * 12];
#pragma unroll
      for (int i = 0; i < 6; ++i) cpk[i] = cv[i];
#pragma unroll
      for (int q = 0; q < 6; ++q) {        // fused RX*RY*RZ
        const int m = 1 << (5 - q);
        float4 M = mats[(l * 6 + q) * 2 + ((lane & m) ? 1 : 0)];
        float pre = __shfl_xor(re, m, 64);
        float pim = __shfl_xor(im, m, 64);
        float nre = M.x * re - M.y * im + M.z * pre - M.w * pim;
        float nim = M.x * im + M.y * re + M.z * pim + M.w * pre;
        re = nre; im = nim;
      }
#pragma unroll
      for (int e = 0; e < 12; ++e) {       // ring CRX fwd then bwd
        const int q = (e < 6) ? e : (11 - e);
        const int mc = 1 << (5 - q);
        const int mt = (e < 6) ? (1 << (5 - ((q + 1) % 6)))
                               : (1 << (5 - ((q + 5) % 6)));
        float2 cs = (e & 1) ? make_float2(cpk[e >> 1].z, cpk[e >> 1].w)
                            : make_float2(cpk[e >> 1].x, cpk[e >> 1].y);
        float pre = __shfl_xor(re, mt, 64);
        float pim = __shfl_xor(im, mt, 64);
        float nre = fmaf(cs.y, pim, cs.x * re);
        float nim = fmaf(-cs.y, pre, cs.x * im);
        bool act = (lane & mc) != 0;
        re = act ? nre : re;
        im = act ? nim : im;
      }
    }
    evolved[((size_t)b * NCH + cq * 4 + wv) * QDIM + lane] = make_float2(re, im);
  }
}

// ============ K3: LCU mix + qff ansatz + expvals + head (512 thr) ============
__global__ __launch_bounds__(512) void k3_head(
    const float2* __restrict__ evolved, const float* __restrict__ mix_re,
    const float* __restrict__ mix_im, const float* __restrict__ qff,
    const float* __restrict__ out_w, const float* __restrict__ out_b,
    const float* __restrict__ ln_g, const float* __restrict__ ln_b,
    const float* __restrict__ cls_w1, const float* __restrict__ cls_b1,
    const float* __restrict__ cls_w2, const float* __restrict__ cls_b2,
    float* __restrict__ outp) {
  const int b = blockIdx.x, tid = threadIdx.x, wv = tid >> 6, lane = tid & 63;
  __shared__ float mreS[8][64], mimS[8][64];
  __shared__ float qfeatS[18];
  __shared__ float outS[DD];
  __shared__ float redS[8];
  __shared__ float clsR[2][DD];

  float are = 0.f, aim = 0.f;
#pragma unroll 4
  for (int t = wv * 16; t < wv * 16 + 16; ++t) {
    float2 e = evolved[((size_t)b * NCH + t) * QDIM + lane];
    float cr = mix_re[t], ci = mix_im[t];
    are = fmaf(cr, e.x, are); are = fmaf(-ci, e.y, are);
    aim = fmaf(cr, e.y, aim); aim = fmaf(ci, e.x, aim);
  }
  mreS[wv][lane] = are; mimS[wv][lane] = aim;
  __syncthreads();

  if (wv == 0) {
    float r0 = mix_re[lane], i0 = mix_im[lane];
    float r1 = mix_re[lane + 64], i1 = mix_im[lane + 64];
    float sp = sqrtf(r0 * r0 + i0 * i0) + sqrtf(r1 * r1 + i1 * i1);
    float S = wave_sum(sp) + 1e-8f;
    float re = 0.f, im = 0.f;
#pragma unroll
    for (int w = 0; w < 8; ++w) { re += mreS[w][lane]; im += mimS[w][lane]; }
    float invS = 1.f / S;
    re *= invS; im *= invS;
    float n2 = wave_sum(re * re + im * im);
    float scl = 1.f / (sqrtf(n2) + 1e-9f);
    re *= scl; im *= scl;
    float qp[30];
#pragma unroll
    for (int i = 0; i < 30; ++i) qp[i] = qff[i];
    ansatz_layer(re, im, lane, qp);
#pragma unroll
    for (int q = 0; q < 6; ++q) {
      int m = 1 << (5 - q);
      float pre = __shfl_xor(re, m, 64), pim = __shfl_xor(im, m, 64);
      float vx = re * pre + im * pim;
      float vy = (lane & m) ? (im * pre - re * pim) : (re * pim - im * pre);
      float vz = (lane & m) ? -(re * re + im * im) : (re * re + im * im);
      vx = wave_sum(vx); vy = wave_sum(vy); vz = wave_sum(vz);
      if (lane == 0) { qfeatS[q] = vx; qfeatS[6 + q] = vy; qfeatS[12 + q] = vz; }
    }
  }
  __syncthreads();

  float o = 0.f, dv = 0.f;
  if (tid < 256) {
    o = out_b[tid];
#pragma unroll
    for (int k = 0; k < 18; ++k) o = fmaf(qfeatS[k], out_w[k * DD + tid], o);
    float s1 = wave_sum(o);
    if (lane == 0) redS[wv] = s1;
  }
  __syncthreads();
  float mu = (redS[0] + redS[1] + redS[2] + redS[3]) * (1.f / 256.f);
  if (tid < 256) {
    dv = o - mu;
    float s2 = wave_sum(dv * dv);
    if (lane == 0) redS[wv] = s2;
  }
  __syncthreads();
  float var = (redS[0] + redS[1] + redS[2] + redS[3]) * (1.f / 256.f);
  if (tid < 256) {
    outS[tid] = dv / sqrtf(var + 1e-5f) * ln_g[tid] + ln_b[tid];
  }
  __syncthreads();

  {
    const int dd = tid & 255, hh = tid >> 8;
    float r = (hh == 0) ? cls_b1[dd] : 0.f;
#pragma unroll 8
    for (int d = hh * 128; d < hh * 128 + 128; ++d)
      r = fmaf(outS[d], cls_w1[(size_t)d * DD + dd], r);
    clsR[hh][dd] = r;
  }
  __syncthreads();
  if (tid < 256) {
    float r = fmaxf(clsR[0][tid] + clsR[1][tid], 0.f);
    float p0 = wave_sum(r * cls_w2[tid * 2 + 0]);
    float p1 = wave_sum(r * cls_w2[tid * 2 + 1]);
    if (lane == 0) { mreS[0][wv] = p0; mreS[1][wv] = p1; }
  }
  __syncthreads();
  if (tid == 0) {
    outp[b * 2 + 0] = (mreS[0][0] + mreS[0][1]) + (mreS[0][2] + mreS[0][3]) + cls_b2[0];
    outp[b * 2 + 1] = (mreS[1][0] + mreS[1][1]) + (mreS[1][2] + mreS[1][3]) + cls_b2[1];
  }
}

extern "C" void kernel_launch(void* const* d_in, const int* in_sizes, int n_in,
                              void* d_out, int out_size, void* d_ws, size_t ws_size,
                              hipStream_t stream) {
  const float* x      = (const float*)d_in[0];
  const float* emb_w  = (const float*)d_in[1];
  const float* emb_b  = (const float*)d_in[2];
  const float* att_w1 = (const float*)d_in[3];
  const float* att_b1 = (const float*)d_in[4];
  const float* att_w2 = (const float*)d_in[5];
  // d_in[6] att_b2: unused (softmax shift-invariant)
  const float* proj_w = (const float*)d_in[7];
  const float* proj_b = (const float*)d_in[8];
  const float* mix_re = (const float*)d_in[9];
  const float* mix_im = (const float*)d_in[10];
  const float* qff    = (const float*)d_in[11];
  const float* out_w  = (const float*)d_in[12];
  const float* out_b  = (const float*)d_in[13];
  const float* ln_g   = (const float*)d_in[14];
  const float* ln_b   = (const float*)d_in[15];
  const float* cls_w1 = (const float*)d_in[16];
  const float* cls_b1 = (const float*)d_in[17];
  const float* cls_w2 = (const float*)d_in[18];
  const float* cls_b2 = (const float*)d_in[19];

  char* ws = (char*)d_ws;
  float2* evolved = (float2*)ws;                     // 16384*64*8 = 8,388,608
  size_t off = 8388608;
  __bf16* WfH = (__bf16*)(ws + off); off += 16384;   // 128x64 bf16
  __bf16* WfL = (__bf16*)(ws + off); off += 16384;
  __bf16* PfH = (__bf16*)(ws + off); off += 8192;    // 64x64 bf16
  __bf16* PfL = (__bf16*)(ws + off); off += 8192;
  float* b_fused  = (float*)(ws + off); off += 512;
  float* pb_fused = (float*)(ws + off); off += 256;

  k0_prep<<<390, 256, 0, stream>>>(emb_w, emb_b, att_w1, att_b1, proj_w, proj_b,
                                   WfH, WfL, PfH, PfL, b_fused, pb_fused);
  k1_fused<<<BB * 32, 256, 0, stream>>>(
      x, att_w2, WfH, WfL, PfH, PfL, b_fused, pb_fused, evolved);
  k3_head<<<BB, 512, 0, stream>>>(evolved, mix_re, mix_im, qff, out_w, out_b,
                                  ln_g, ln_b, cls_w1, cls_b1, cls_w2, cls_b2,
                                  (float*)d_out);
}

// Round 11
// 193.001 us; speedup vs baseline: 1.0855x; 1.0855x over previous
//
#include <hip/hip_runtime.h>
#include <math.h>

#define NQ    6
#define QDIM  64
#define BB    128
#define CC    64
#define TT    2048
#define DD    256
#define NCH   128
#define CHLEN 16
#define HH    128
#define NCP   60

typedef __bf16 bf16x8 __attribute__((ext_vector_type(8)));
typedef float  f32x4  __attribute__((ext_vector_type(4)));

__device__ __forceinline__ unsigned short bfbits(__bf16 v) {
  return __builtin_bit_cast(unsigned short, v);
}

__device__ __forceinline__ float fast_tanh(float x) {
  float e = __expf(2.f * x);
  return 1.f - 2.f / (e + 1.f);
}

__device__ __forceinline__ float wave_sum(float v) {
#pragma unroll
  for (int off = 32; off >= 1; off >>= 1) v += __shfl_xor(v, off, 64);
  return v;
}

// ---- quantum gates (k3 path keeps the trig-per-gate form; k1 uses fused) ----
__device__ __forceinline__ void g_rx(float& re, float& im, int lane, int m, float half) {
  float c = __cosf(half), s = __sinf(half);
  float pre = __shfl_xor(re, m, 64);
  float pim = __shfl_xor(im, m, 64);
  float nre = c * re + s * pim;
  float nim = c * im - s * pre;
  re = nre; im = nim;
}
__device__ __forceinline__ void g_ry(float& re, float& im, int lane, int m, float half) {
  float c = __cosf(half), s = __sinf(half);
  float pre = __shfl_xor(re, m, 64);
  float pim = __shfl_xor(im, m, 64);
  float sg = (lane & m) ? s : -s;
  re = c * re + sg * pre;
  im = c * im + sg * pim;
}
__device__ __forceinline__ void g_rz(float& re, float& im, int lane, int m, float half) {
  float c = __cosf(half), s = __sinf(half);
  float sg = (lane & m) ? s : -s;
  float nre = c * re - sg * im;
  float nim = c * im + sg * re;
  re = nre; im = nim;
}
__device__ __forceinline__ void g_crx(float& re, float& im, int lane, int mc, int mt, float half) {
  float c = __cosf(half), s = __sinf(half);
  float pre = __shfl_xor(re, mt, 64);
  float pim = __shfl_xor(im, mt, 64);
  if (lane & mc) {
    float nre = c * re + s * pim;
    float nim = c * im - s * pre;
    re = nre; im = nim;
  }
}
__device__ __forceinline__ void ansatz_layer(float& re, float& im, int lane,
                                             const float* p) {
#pragma unroll
  for (int q = 0; q < 6; ++q) {
    int m = 1 << (5 - q);
    g_rx(re, im, lane, m, 0.5f * p[3 * q + 0]);
    g_ry(re, im, lane, m, 0.5f * p[3 * q + 1]);
    g_rz(re, im, lane, m, 0.5f * p[3 * q + 2]);
  }
#pragma unroll
  for (int q = 0; q < 6; ++q)
    g_crx(re, im, lane, 1 << (5 - q), 1 << (5 - ((q + 1) % 6)), 0.5f * p[18 + q]);
#pragma unroll
  for (int q = 5; q >= 0; --q)
    g_crx(re, im, lane, 1 << (5 - q), 1 << (5 - ((q + 5) % 6)), 0.5f * p[24 + (5 - q)]);
}

// ============ K0: fused-weight prep, 8-way split-K (390 blocks) =============
__global__ __launch_bounds__(256) void k0_prep(
    const float* __restrict__ emb_w, const float* __restrict__ emb_b,
    const float* __restrict__ att_w1, const float* __restrict__ att_b1,
    const float* __restrict__ proj_w, const float* __restrict__ proj_b,
    __bf16* __restrict__ WfH, __bf16* __restrict__ WfL,
    __bf16* __restrict__ PfH, __bf16* __restrict__ PfL,
    float* __restrict__ b_fused, float* __restrict__ pb_fused) {
  int idx = blockIdx.x * 256 + threadIdx.x;
  if (idx < 65536) {                        // W_fusedT: 8192 outs x 8 parts
    int out = idx >> 3, part = idx & 7;
    int j = out & 127, k = out >> 7;
    int d0 = part * 32;
    float a = 0.f;
#pragma unroll 8
    for (int d = d0; d < d0 + 32; ++d)
      a = fmaf(emb_w[k * 256 + d], att_w1[d * 128 + j], a);
    a += __shfl_xor(a, 1, 64); a += __shfl_xor(a, 2, 64); a += __shfl_xor(a, 4, 64);
    if (part == 0) {
      __bf16 h = (__bf16)a;
      WfH[j * 64 + k] = h; WfL[j * 64 + k] = (__bf16)(a - (float)h);
    }
  } else if (idx < 98304) {                 // P_fusedT: 4096 outs x 8 parts
    int i2 = idx - 65536;
    int out = i2 >> 3, part = i2 & 7;
    int n = out & 63, k = out >> 6;
    float a = 0.f;
    if (n < 60) {
      int d0 = part * 32;
#pragma unroll 8
      for (int d = d0; d < d0 + 32; ++d)
        a = fmaf(emb_w[k * 256 + d], proj_w[d * 60 + n], a);
    }
    a += __shfl_xor(a, 1, 64); a += __shfl_xor(a, 2, 64); a += __shfl_xor(a, 4, 64);
    if (part == 0) {
      __bf16 h = (__bf16)a;
      PfH[n * 64 + k] = h; PfL[n * 64 + k] = (__bf16)(a - (float)h);
    }
  } else if (idx < 99328) {                 // b_fused: 128 outs x 8
    int i3 = idx - 98304;
    int out = i3 >> 3, part = i3 & 7;
    float a = (part == 0) ? att_b1[out] : 0.f;
    int d0 = part * 32;
#pragma unroll 8
    for (int d = d0; d < d0 + 32; ++d)
      a = fmaf(emb_b[d], att_w1[d * 128 + out], a);
    a += __shfl_xor(a, 1, 64); a += __shfl_xor(a, 2, 64); a += __shfl_xor(a, 4, 64);
    if (part == 0) b_fused[out] = a;
  } else if (idx < 99840) {                 // pb_fused: 64 outs x 8
    int i4 = idx - 99328;
    int out = i4 >> 3, part = i4 & 7;
    float a = 0.f;
    if (out < 60) {
      if (part == 0) a = proj_b[out];
      int d0 = part * 32;
#pragma unroll 8
      for (int d = d0; d < d0 + 32; ++d)
        a = fmaf(emb_b[d], proj_w[d * 60 + out], a);
    }
    a += __shfl_xor(a, 1, 64); a += __shfl_xor(a, 2, 64); a += __shfl_xor(a, 4, 64);
    if (part == 0) pb_fused[out] = a;
  }
}

// ============ K1: fused h-GEMM + softmax + bilinear params + ansatz ==========
// BEST MEASURED (R7: total 193.3us, k1 ~71us, VGPR 52, no spill).
// Session post-mortems locked in here:
//  - natural register allocation ONLY: forcing waves/EU (R3, R10) always
//    spills (~140MB scratch traffic) and cancels the occupancy gain
//  - occupancy ~38% is a stable equilibrium: k1 is issue+latency bound,
//    insensitive to residency (29%..68% all ~71-80us)
//  - bilinear params path (F') must be liveness-separated from score GEMM
//    (R4 interleaved variant: +22us of stall)
// Phases: A stage | C score GEMM (jt-inner, frags hoisted) | D softmax
//  | F' XP GEMM + bilinear w-reduce | G fused 1q mats | H ansatz (trig-free).
__global__ __launch_bounds__(256) void k1_fused(
    const float* __restrict__ x, const float* __restrict__ att_w2,
    const __bf16* __restrict__ WfH, const __bf16* __restrict__ WfL,
    const __bf16* __restrict__ PfH, const __bf16* __restrict__ PfL,
    const float* __restrict__ b_fused, const float* __restrict__ pb_fused,
    float2* __restrict__ evolved) {
  const int blk = blockIdx.x;            // 4096 = 128 b x 32 chunk-quads
  const int b = blk >> 5, cq = blk & 31;
  const int tid = threadIdx.x, wv = tid >> 6, lane = tid & 63;
  const int l15 = lane & 15, quad = lane >> 4;

  __shared__ float4 afF4[1024];          // 16 KB split-bf16 A-frags (H | L)
  __shared__ float scoreS[4][64];        // 1 KB
  __shared__ __align__(16) float wSm[4][16];   // 256 B
  __shared__ float paramsS[4][60];       // 960 B
  __shared__ float4 matS[96];            // [4 chunk][12 gate][2]  1536 B
  __shared__ float2 crxS[96];            // [4 chunk][24]          768 B

  bf16x8* afH = (bf16x8*)afF4;                       // [8 frag][64 lane]
  bf16x8* afL = (bf16x8*)((char*)afF4 + 8192);

  {  // A: stage x -> split-bf16 MFMA fragments directly (k-pairs, ushort2)
    unsigned short* afHu = (unsigned short*)afF4;
    unsigned short* afLu = (unsigned short*)((char*)afF4 + 8192);
#pragma unroll
    for (int p = 0; p < 2; ++p) {
      int slot = p * 256 + tid;
      int t4 = slot & 15, kp = slot >> 4;       // kp 0..31
      int k0 = kp * 2;
      const float* base = x + ((size_t)(b * 64 + k0)) * 2048 + cq * 64 + t4 * 4;
      float4 v0 = *(const float4*)base;
      float4 v1 = *(const float4*)(base + 2048);
      int ks = k0 >> 5, colq = (k0 >> 3) & 3, e = k0 & 7;
      float a0[4] = {v0.x, v0.y, v0.z, v0.w};
      float a1[4] = {v1.x, v1.y, v1.z, v1.w};
#pragma unroll
      for (int dt = 0; dt < 4; ++dt) {
        int t = t4 * 4 + dt;
        int frag = (t >> 4) * 2 + ks;
        int ln = (t & 15) + colq * 16;
        int widx = frag * 512 + ln * 8 + e;     // ushort index (e even)
        __bf16 h0 = (__bf16)a0[dt]; __bf16 l0 = (__bf16)(a0[dt] - (float)h0);
        __bf16 h1 = (__bf16)a1[dt]; __bf16 l1 = (__bf16)(a1[dt] - (float)h1);
        *(ushort2*)(afHu + widx) = make_ushort2(bfbits(h0), bfbits(h1));
        *(ushort2*)(afLu + widx) = make_ushort2(bfbits(l0), bfbits(l1));
      }
    }
  }
  __syncthreads();

  // ---- C: GEMM_h in two 2-chunk halves; wave owns j = wv*32..+31 ----
  {
    float w2v[2], b1v[2];
#pragma unroll
    for (int jt = 0; jt < 2; ++jt) {
      int j = wv * 32 + jt * 16 + l15;
      w2v[jt] = att_w2[j];
      b1v[jt] = b_fused[j];
    }
#pragma unroll
    for (int half = 0; half < 2; ++half) {
      f32x4 acc[2][2];                   // [mtl][jt]
#pragma unroll
      for (int a2 = 0; a2 < 2; ++a2)
#pragma unroll
        for (int c2 = 0; c2 < 2; ++c2) acc[a2][c2] = (f32x4){0.f, 0.f, 0.f, 0.f};
#pragma unroll
      for (int ks = 0; ks < 2; ++ks) {
        bf16x8 ah[2], al[2];             // hoisted: each frag read ONCE
#pragma unroll
        for (int mtl = 0; mtl < 2; ++mtl) {
          int frag = (half * 2 + mtl) * 2 + ks;
          ah[mtl] = afH[frag * 64 + lane];
          al[mtl] = afL[frag * 64 + lane];
        }
#pragma unroll
        for (int jt = 0; jt < 2; ++jt) {
          const size_t row = (size_t)(wv * 32 + jt * 16 + l15) * 64 + ks * 32 + 8 * quad;
          bf16x8 bh = *(const bf16x8*)(WfH + row);
          bf16x8 bl = *(const bf16x8*)(WfL + row);
#pragma unroll
          for (int mtl = 0; mtl < 2; ++mtl) {
            acc[mtl][jt] = __builtin_amdgcn_mfma_f32_16x16x32_bf16(ah[mtl], bh, acc[mtl][jt], 0, 0, 0);
            acc[mtl][jt] = __builtin_amdgcn_mfma_f32_16x16x32_bf16(al[mtl], bh, acc[mtl][jt], 0, 0, 0);
            acc[mtl][jt] = __builtin_amdgcn_mfma_f32_16x16x32_bf16(ah[mtl], bl, acc[mtl][jt], 0, 0, 0);
          }
        }
      }
      // epilogue: tanh, * w2, reduce over the 16 j's in l15
#pragma unroll
      for (int mtl = 0; mtl < 2; ++mtl)
#pragma unroll
        for (int r = 0; r < 4; ++r) {
          float sc = fast_tanh(acc[mtl][0][r] + b1v[0]) * w2v[0] +
                     fast_tanh(acc[mtl][1][r] + b1v[1]) * w2v[1];
          sc += __shfl_xor(sc, 1, 64);
          sc += __shfl_xor(sc, 2, 64);
          sc += __shfl_xor(sc, 4, 64);
          sc += __shfl_xor(sc, 8, 64);
          if (l15 == 0) scoreS[wv][(half * 2 + mtl) * 16 + quad * 4 + r] = sc;
        }
    }
  }
  __syncthreads();

  if (tid < 64) {  // D: parallel softmax, 16 lanes per chunk (att_b2 dropped)
    const int c = tid >> 4, t = tid & 15, ct = c * 16 + t;
    float s = (scoreS[0][ct] + scoreS[1][ct]) + (scoreS[2][ct] + scoreS[3][ct]);
    float mx = s;
    mx = fmaxf(mx, __shfl_xor(mx, 1, 64));
    mx = fmaxf(mx, __shfl_xor(mx, 2, 64));
    mx = fmaxf(mx, __shfl_xor(mx, 4, 64));
    mx = fmaxf(mx, __shfl_xor(mx, 8, 64));
    float e = __expf(s - mx);
    float sum = e;
    sum += __shfl_xor(sum, 1, 64);
    sum += __shfl_xor(sum, 2, 64);
    sum += __shfl_xor(sum, 4, 64);
    sum += __shfl_xor(sum, 8, 64);
    wSm[c][t] = e / sum;
  }
  __syncthreads();

  {  // F': XP GEMM (A-frags from LDS, reg-local accp) + bilinear w-reduce
     // accp[mt]: rows = t of chunk mt (quad*4+r), cols n = wv*16+l15
    const size_t prow = (size_t)(wv * 16 + l15) * 64 + 8 * quad;
    f32x4 accp[4];
#pragma unroll
    for (int c = 0; c < 4; ++c) accp[c] = (f32x4){0.f, 0.f, 0.f, 0.f};
#pragma unroll
    for (int ks = 0; ks < 2; ++ks) {
      bf16x8 pbh = *(const bf16x8*)(PfH + prow + ks * 32);
      bf16x8 pbl = *(const bf16x8*)(PfL + prow + ks * 32);
#pragma unroll
      for (int mt = 0; mt < 4; ++mt) {
        bf16x8 ah = afH[(mt * 2 + ks) * 64 + lane];
        bf16x8 al = afL[(mt * 2 + ks) * 64 + lane];
        accp[mt] = __builtin_amdgcn_mfma_f32_16x16x32_bf16(ah, pbh, accp[mt], 0, 0, 0);
        accp[mt] = __builtin_amdgcn_mfma_f32_16x16x32_bf16(al, pbh, accp[mt], 0, 0, 0);
        accp[mt] = __builtin_amdgcn_mfma_f32_16x16x32_bf16(ah, pbl, accp[mt], 0, 0, 0);
      }
    }
    float v[4];
#pragma unroll
    for (int c = 0; c < 4; ++c) {       // params_pre[c][n] = sum_t w[c][t]*XP
      float4 wq = *(const float4*)&wSm[c][quad * 4];
      float a = wq.x * accp[c][0] + wq.y * accp[c][1] +
                wq.z * accp[c][2] + wq.w * accp[c][3];
      a += __shfl_xor(a, 16, 64);
      a += __shfl_xor(a, 32, 64);
      v[c] = a;
    }
    const int n = wv * 16 + l15;
    if (quad == 0 && n < 60) {
      float pbias = pb_fused[n];
      const int layer = (n >= 30) ? 1 : 0;
      const int pm = n - layer * 30;
#pragma unroll
      for (int c = 0; c < 4; ++c) {
        float a = v[c] + pbias;
        float p = 1.f / (1.f + __expf(-a));
        paramsS[c][n] = p;
        if (pm >= 18) {                 // CRX param: stash (cos,sin) of half
          float sn, cs;
          __sincosf(0.5f * p, &sn, &cs);
          crxS[c * 24 + layer * 12 + (pm - 18)] = make_float2(cs, sn);
        }
      }
    }
  }
  __syncthreads();

  if (tid < 48) {  // G: fused 1q unitary U = Rz*Ry*Rx per (chunk,layer,qubit)
    const int r = tid / 12, g = tid % 12;      // g = layer*6 + q
    const float* pp = &paramsS[r][(g / 6) * 30 + (g % 6) * 3];
    float sa, ca, sb, cb, sg, cg;
    __sincosf(0.5f * pp[0], &sa, &ca);
    __sincosf(0.5f * pp[1], &sb, &cb);
    __sincosf(0.5f * pp[2], &sg, &cg);
    // M = Ry*Rx
    float m00r = cb * ca, m00i = sb * sa;
    float m01r = -sb * ca, m01i = -cb * sa;
    float m10r = sb * ca, m10i = -cb * sa;
    float m11r = cb * ca, m11i = -sb * sa;
    // row0 *= e^{-i g}; row1 *= e^{+i g}; store per-bit {diag, offdiag}
    float4 b0, b1;
    b0.x = cg * m00r + sg * m00i;  b0.y = cg * m00i - sg * m00r;   // U00
    b0.z = cg * m01r + sg * m01i;  b0.w = cg * m01i - sg * m01r;   // U01
    b1.x = cg * m11r - sg * m11i;  b1.y = cg * m11i + sg * m11r;   // U11
    b1.z = cg * m10r - sg * m10i;  b1.w = cg * m10i + sg * m10r;   // U10
    matS[(r * 12 + g) * 2 + 0] = b0;
    matS[(r * 12 + g) * 2 + 1] = b1;
  }
  __syncthreads();

  // ---- H: ALL 4 waves evolve one chunk each (trig-free loop) ----
  {
    float re = (lane == 0) ? 1.f : 0.f, im = 0.f;
    const float4* mats = &matS[wv * 24];   // [12][2]
    const float2* crxs = &crxS[wv * 24];   // [2][12]
#pragma unroll
    for (int l = 0; l < 2; ++l) {
#pragma unroll
      for (int q = 0; q < 6; ++q) {        // fused RX*RY*RZ
        const int m = 1 << (5 - q);
        float4 M = mats[(l * 6 + q) * 2 + ((lane & m) ? 1 : 0)];
        float pre = __shfl_xor(re, m, 64);
        float pim = __shfl_xor(im, m, 64);
        float nre = M.x * re - M.y * im + M.z * pre - M.w * pim;
        float nim = M.x * im + M.y * re + M.z * pim + M.w * pre;
        re = nre; im = nim;
      }
#pragma unroll
      for (int e = 0; e < 12; ++e) {       // ring CRX fwd then bwd
        const int q = (e < 6) ? e : (11 - e);
        const int mc = 1 << (5 - q);
        const int mt = (e < 6) ? (1 << (5 - ((q + 1) % 6)))
                               : (1 << (5 - ((q + 5) % 6)));
        float2 cs = crxs[l * 12 + e];
        float pre = __shfl_xor(re, mt, 64);
        float pim = __shfl_xor(im, mt, 64);
        float nre = fmaf(cs.y, pim, cs.x * re);
        float nim = fmaf(-cs.y, pre, cs.x * im);
        bool act = (lane & mc) != 0;
        re = act ? nre : re;
        im = act ? nim : im;
      }
    }
    evolved[((size_t)b * NCH + cq * 4 + wv) * QDIM + lane] = make_float2(re, im);
  }
}

// ============ K3: LCU mix + qff ansatz + expvals + head (512 thr) ============
__global__ __launch_bounds__(512) void k3_head(
    const float2* __restrict__ evolved, const float* __restrict__ mix_re,
    const float* __restrict__ mix_im, const float* __restrict__ qff,
    const float* __restrict__ out_w, const float* __restrict__ out_b,
    const float* __restrict__ ln_g, const float* __restrict__ ln_b,
    const float* __restrict__ cls_w1, const float* __restrict__ cls_b1,
    const float* __restrict__ cls_w2, const float* __restrict__ cls_b2,
    float* __restrict__ outp) {
  const int b = blockIdx.x, tid = threadIdx.x, wv = tid >> 6, lane = tid & 63;
  __shared__ float mreS[8][64], mimS[8][64];
  __shared__ float qfeatS[18];
  __shared__ float outS[DD];
  __shared__ float redS[8];
  __shared__ float clsR[2][DD];

  float are = 0.f, aim = 0.f;
#pragma unroll 4
  for (int t = wv * 16; t < wv * 16 + 16; ++t) {
    float2 e = evolved[((size_t)b * NCH + t) * QDIM + lane];
    float cr = mix_re[t], ci = mix_im[t];
    are = fmaf(cr, e.x, are); are = fmaf(-ci, e.y, are);
    aim = fmaf(cr, e.y, aim); aim = fmaf(ci, e.x, aim);
  }
  mreS[wv][lane] = are; mimS[wv][lane] = aim;
  __syncthreads();

  if (wv == 0) {
    float r0 = mix_re[lane], i0 = mix_im[lane];
    float r1 = mix_re[lane + 64], i1 = mix_im[lane + 64];
    float sp = sqrtf(r0 * r0 + i0 * i0) + sqrtf(r1 * r1 + i1 * i1);
    float S = wave_sum(sp) + 1e-8f;
    float re = 0.f, im = 0.f;
#pragma unroll
    for (int w = 0; w < 8; ++w) { re += mreS[w][lane]; im += mimS[w][lane]; }
    float invS = 1.f / S;
    re *= invS; im *= invS;
    float n2 = wave_sum(re * re + im * im);
    float scl = 1.f / (sqrtf(n2) + 1e-9f);
    re *= scl; im *= scl;
    float qp[30];
#pragma unroll
    for (int i = 0; i < 30; ++i) qp[i] = qff[i];
    ansatz_layer(re, im, lane, qp);
#pragma unroll
    for (int q = 0; q < 6; ++q) {
      int m = 1 << (5 - q);
      float pre = __shfl_xor(re, m, 64), pim = __shfl_xor(im, m, 64);
      float vx = re * pre + im * pim;
      float vy = (lane & m) ? (im * pre - re * pim) : (re * pim - im * pre);
      float vz = (lane & m) ? -(re * re + im * im) : (re * re + im * im);
      vx = wave_sum(vx); vy = wave_sum(vy); vz = wave_sum(vz);
      if (lane == 0) { qfeatS[q] = vx; qfeatS[6 + q] = vy; qfeatS[12 + q] = vz; }
    }
  }
  __syncthreads();

  float o = 0.f, dv = 0.f;
  if (tid < 256) {
    o = out_b[tid];
#pragma unroll
    for (int k = 0; k < 18; ++k) o = fmaf(qfeatS[k], out_w[k * DD + tid], o);
    float s1 = wave_sum(o);
    if (lane == 0) redS[wv] = s1;
  }
  __syncthreads();
  float mu = (redS[0] + redS[1] + redS[2] + redS[3]) * (1.f / 256.f);
  if (tid < 256) {
    dv = o - mu;
    float s2 = wave_sum(dv * dv);
    if (lane == 0) redS[wv] = s2;
  }
  __syncthreads();
  float var = (redS[0] + redS[1] + redS[2] + redS[3]) * (1.f / 256.f);
  if (tid < 256) {
    outS[tid] = dv / sqrtf(var + 1e-5f) * ln_g[tid] + ln_b[tid];
  }
  __syncthreads();

  {
    const int dd = tid & 255, hh = tid >> 8;
    float r = (hh == 0) ? cls_b1[dd] : 0.f;
#pragma unroll 8
    for (int d = hh * 128; d < hh * 128 + 128; ++d)
      r = fmaf(outS[d], cls_w1[(size_t)d * DD + dd], r);
    clsR[hh][dd] = r;
  }
  __syncthreads();
  if (tid < 256) {
    float r = fmaxf(clsR[0][tid] + clsR[1][tid], 0.f);
    float p0 = wave_sum(r * cls_w2[tid * 2 + 0]);
    float p1 = wave_sum(r * cls_w2[tid * 2 + 1]);
    if (lane == 0) { mreS[0][wv] = p0; mreS[1][wv] = p1; }
  }
  __syncthreads();
  if (tid == 0) {
    outp[b * 2 + 0] = (mreS[0][0] + mreS[0][1]) + (mreS[0][2] + mreS[0][3]) + cls_b2[0];
    outp[b * 2 + 1] = (mreS[1][0] + mreS[1][1]) + (mreS[1][2] + mreS[1][3]) + cls_b2[1];
  }
}

extern "C" void kernel_launch(void* const* d_in, const int* in_sizes, int n_in,
                              void* d_out, int out_size, void* d_ws, size_t ws_size,
                              hipStream_t stream) {
  const float* x      = (const float*)d_in[0];
  const float* emb_w  = (const float*)d_in[1];
  const float* emb_b  = (const float*)d_in[2];
  const float* att_w1 = (const float*)d_in[3];
  const float* att_b1 = (const float*)d_in[4];
  const float* att_w2 = (const float*)d_in[5];
  // d_in[6] att_b2: unused (softmax shift-invariant)
  const float* proj_w = (const float*)d_in[7];
  const float* proj_b = (const float*)d_in[8];
  const float* mix_re = (const float*)d_in[9];
  const float* mix_im = (const float*)d_in[10];
  const float* qff    = (const float*)d_in[11];
  const float* out_w  = (const float*)d_in[12];
  const float* out_b  = (const float*)d_in[13];
  const float* ln_g   = (const float*)d_in[14];
  const float* ln_b   = (const float*)d_in[15];
  const float* cls_w1 = (const float*)d_in[16];
  const float* cls_b1 = (const float*)d_in[17];
  const float* cls_w2 = (const float*)d_in[18];
  const float* cls_b2 = (const float*)d_in[19];

  char* ws = (char*)d_ws;
  float2* evolved = (float2*)ws;                     // 16384*64*8 = 8,388,608
  size_t off = 8388608;
  __bf16* WfH = (__bf16*)(ws + off); off += 16384;   // 128x64 bf16
  __bf16* WfL = (__bf16*)(ws + off); off += 16384;
  __bf16* PfH = (__bf16*)(ws + off); off += 8192;    // 64x64 bf16
  __bf16* PfL = (__bf16*)(ws + off); off += 8192;
  float* b_fused  = (float*)(ws + off); off += 512;
  float* pb_fused = (float*)(ws + off); off += 256;

  k0_prep<<<390, 256, 0, stream>>>(emb_w, emb_b, att_w1, att_b1, proj_w, proj_b,
                                   WfH, WfL, PfH, PfL, b_fused, pb_fused);
  k1_fused<<<BB * 32, 256, 0, stream>>>(
      x, att_w2, WfH, WfL, PfH, PfL, b_fused, pb_fused, evolved);
  k3_head<<<BB, 512, 0, stream>>>(evolved, mix_re, mix_im, qff, out_w, out_b,
                                  ln_g, ln_b, cls_w1, cls_b1, cls_w2, cls_b2,
                                  (float*)d_out);
}